// Round 4
// baseline (303.715 us; speedup 1.0000x reference)
//
#include <hip/hip_runtime.h>

#define KK 21
#define HH 512
#define WW 512
#define CC 3
#define BB 32
#define TILE_Y 64
#define TILE_X 128
#define SROWS 85        // 2-kh packing reads rows up to 16*3+15+1+20 = 84
#define SSTRIDE 168     // ushort elems/row; 336 B = odd multiple of 16B
#define NKHP 11         // ceil(21/2) kh-pairs; kh=21 is a zero row in B
#define NB_PER_B (NKHP * 3 * 512)   // 16896 bf16 elems per batch
#define NCHUNK 20       // 8-ushort (16B) staging chunks per row: lc in [0,160)
#define NSTG (SROWS * NCHUNK)       // 1700 staged chunks per tile
#define NTHREADS 384    // 6 waves: 4 compute + 2 producer
#define NCOMPUTE 4
#define TILES_PER_BLK 6
#define NBLK 512        // 512 blocks * 6 tiles = 3072 tiles; exactly 2 blocks/CU

typedef __attribute__((ext_vector_type(8))) short short8;
typedef __attribute__((ext_vector_type(4))) float floatx4;

__device__ __forceinline__ unsigned short f2bf(float f) {
    union { float f; unsigned u; } v; v.f = f;
    unsigned r = v.u + 0x7FFF + ((v.u >> 16) & 1);   // RNE
    return (unsigned short)(r >> 16);
}

// ---- kernel 1: build banded-Toeplitz B fragments (2 kernel rows packed per K=32) ----
// el = khp*1536 + half*512 + (q*16 + n)*8 + j   (bf16)
// k = q*8+j; h = k>>4 (selects kernel row 2*khp+h); c = k&15
// tap d = c - n - 2 + 16*half  (staged origin gx = tx0 - 12 + lc)
__global__ __launch_bounds__(256) void build_B(
    const float* __restrict__ ker, unsigned short* __restrict__ wsB)
{
    const int b = blockIdx.x;
    const float* __restrict__ kp = ker + b * KK * KK;
    unsigned short* __restrict__ wb = wsB + (size_t)b * NB_PER_B;
    for (int e = threadIdx.x; e < NB_PER_B; e += 256) {
        const int j    = e & 7;
        const int n    = (e >> 3) & 15;
        const int q    = (e >> 7) & 3;
        const int f    = e >> 9;           // khp*3 + half
        const int khp  = f / 3;
        const int half = f - khp * 3;
        const int k    = q * 8 + j;
        const int h    = k >> 4;
        const int c    = k & 15;
        const int kh   = 2 * khp + h;
        const int d    = c - n - 2 + 16 * half;
        float v = 0.0f;
        if (kh < KK && d >= 0 && d < KK) v = kp[kh * KK + d];
        wb[e] = f2bf(v);
    }
}

// ---- producer-side helpers ----
__device__ __forceinline__ void ld_chunk(
    const float* __restrict__ xp, int ty0, int tx0, int i,
    float4& v0, float4& v1)
{
    const int ly  = i / NCHUNK;
    const int k   = i - ly * NCHUNK;
    const int gy  = ty0 - 10 + ly;
    const int gx0 = tx0 - 12 + 8 * k;              // float4-aligned
    v0 = make_float4(0.f, 0.f, 0.f, 0.f);
    v1 = make_float4(0.f, 0.f, 0.f, 0.f);
    if (gy >= 0 && gy < HH) {
        const float* __restrict__ rp = xp + (size_t)gy * WW;
        if (gx0 >= 0 && gx0 + 7 < WW) {
            v0 = *(const float4*)(rp + gx0);
            v1 = *(const float4*)(rp + gx0 + 4);
        } else {
            if (gx0 + 0 >= 0 && gx0 + 0 < WW) v0.x = rp[gx0 + 0];
            if (gx0 + 1 >= 0 && gx0 + 1 < WW) v0.y = rp[gx0 + 1];
            if (gx0 + 2 >= 0 && gx0 + 2 < WW) v0.z = rp[gx0 + 2];
            if (gx0 + 3 >= 0 && gx0 + 3 < WW) v0.w = rp[gx0 + 3];
            if (gx0 + 4 >= 0 && gx0 + 4 < WW) v1.x = rp[gx0 + 4];
            if (gx0 + 5 >= 0 && gx0 + 5 < WW) v1.y = rp[gx0 + 5];
            if (gx0 + 6 >= 0 && gx0 + 6 < WW) v1.z = rp[gx0 + 6];
            if (gx0 + 7 >= 0 && gx0 + 7 < WW) v1.w = rp[gx0 + 7];
        }
    }
}

__device__ __forceinline__ void wr_chunk(
    unsigned short* __restrict__ sbuf, int i,
    const float4& v0, const float4& v1)
{
    const int ly = i / NCHUNK;
    const int k  = i - ly * NCHUNK;
    const int p0 = (int)((unsigned)f2bf(v0.x) | ((unsigned)f2bf(v0.y) << 16));
    const int p1 = (int)((unsigned)f2bf(v0.z) | ((unsigned)f2bf(v0.w) << 16));
    const int p2 = (int)((unsigned)f2bf(v1.x) | ((unsigned)f2bf(v1.y) << 16));
    const int p3 = (int)((unsigned)f2bf(v1.z) | ((unsigned)f2bf(v1.w) << 16));
    *(int4*)&sbuf[ly * SSTRIDE + 8 * k] = make_int4(p0, p1, p2, p3);  // 16B aligned
}

// producer waves (128 lanes): stage one tile, 4-deep load pipeline
__device__ __forceinline__ void stage_tile(
    const float* __restrict__ x, unsigned short* __restrict__ sbuf,
    int t, int ptid)
{
    const int bc  = t >> 5;                  // 32 tiles per (image,channel)
    const int rem = t & 31;
    const int ty0 = (rem >> 2) * TILE_Y;
    const int tx0 = (rem & 3) * TILE_X;
    const float* __restrict__ xp = x + (size_t)bc * HH * WW;

    for (int i0 = ptid; i0 < NSTG; i0 += 512) {   // 4 strided chunks per pass
        float4 a0, a1, b0, b1, c0, c1, d0, d1;
        const int i1 = i0 + 128, i2 = i0 + 256, i3 = i0 + 384;
        ld_chunk(xp, ty0, tx0, i0, a0, a1);
        if (i1 < NSTG) ld_chunk(xp, ty0, tx0, i1, b0, b1);
        if (i2 < NSTG) ld_chunk(xp, ty0, tx0, i2, c0, c1);
        if (i3 < NSTG) ld_chunk(xp, ty0, tx0, i3, d0, d1);
        wr_chunk(sbuf, i0, a0, a1);
        if (i1 < NSTG) wr_chunk(sbuf, i1, b0, b1);
        if (i2 < NSTG) wr_chunk(sbuf, i2, c0, c1);
        if (i3 < NSTG) wr_chunk(sbuf, i3, d0, d1);
    }
}

// ---- kernel 2: producer-consumer MFMA conv; double-buffered LDS ----
__global__ __launch_bounds__(NTHREADS, 3) void dwconv_mfma(
    const float* __restrict__ x,
    const unsigned short* __restrict__ wsB,
    float* __restrict__ out)
{
    __shared__ __align__(16) unsigned short s_in[2][SROWS * SSTRIDE];  // 2 x 28560 B

    // bijective XCD-aware remap: 512 = 8 XCDs * 64
    const int rbid   = (blockIdx.x & 7) * (NBLK / 8) + (blockIdx.x >> 3);
    const int t_base = rbid * TILES_PER_BLK;
    const int tid  = threadIdx.x;
    const int wv   = tid >> 6;
    const int lane = tid & 63;
    const int mrow = lane & 15;      // A's m / B's n / D's col
    const int qd   = lane >> 4;      // k-chunk: h = qd>>1 (kernel row), col half = qd&1
    const bool producer = (wv >= NCOMPUTE);
    const int ptid = tid - NCOMPUTE * 64;     // 0..127 for producers

    // prologue: stage tile 0 into buf 0
    if (producer) stage_tile(x, s_in[0], t_base, ptid);
    __syncthreads();

    for (int i = 0; i < TILES_PER_BLK; ++i) {
        const int t = t_base + i;
        if (producer) {
            if (i + 1 < TILES_PER_BLK)
                stage_tile(x, s_in[(i + 1) & 1], t + 1, ptid);
        } else {
            const int bc  = t >> 5;
            const int rem = t & 31;
            const int ty0 = (rem >> 2) * TILE_Y;
            const int tx0 = (rem & 3) * TILE_X;
            const int b   = bc / CC;
            const unsigned short* __restrict__ sbuf = s_in[i & 1];
            const unsigned short* bbase = wsB + (size_t)b * NB_PER_B + lane * 8;
            const unsigned short* abase = sbuf + ((16 * wv + mrow + (qd >> 1)) * SSTRIDE) + 8 * (qd & 1);

            floatx4 acc[8];
#pragma unroll
            for (int tt = 0; tt < 8; ++tt) acc[tt] = (floatx4){0.f, 0.f, 0.f, 0.f};

            short8 nb1 = *(const short8*)(bbase);
            short8 nb2 = *(const short8*)(bbase + 512);
            short8 nb3 = *(const short8*)(bbase + 1024);

#pragma unroll 1
            for (int khp = 0; khp < NKHP; ++khp) {
                const short8 b1 = nb1;
                const short8 b2 = nb2;
                const short8 b3 = nb3;
                const int khn = (khp < NKHP - 1) ? (khp + 1) : khp;   // clamped prefetch
                nb1 = *(const short8*)(bbase + khn * 1536);
                nb2 = *(const short8*)(bbase + khn * 1536 + 512);
                nb3 = *(const short8*)(bbase + khn * 1536 + 1024);

                const unsigned short* arow = abase + 2 * khp * SSTRIDE;
                short8 a[10];
#pragma unroll
                for (int s = 0; s < 10; ++s) a[s] = *(const short8*)(arow + 16 * s);

#pragma unroll
                for (int tt = 0; tt < 8; ++tt) {
                    acc[tt] = __builtin_amdgcn_mfma_f32_16x16x32_bf16(a[tt],     b1, acc[tt], 0, 0, 0);
                    acc[tt] = __builtin_amdgcn_mfma_f32_16x16x32_bf16(a[tt + 1], b2, acc[tt], 0, 0, 0);
                    acc[tt] = __builtin_amdgcn_mfma_f32_16x16x32_bf16(a[tt + 2], b3, acc[tt], 0, 0, 0);
                }
            }

            // epilogue: D layout col=lane&15, row=(lane>>4)*4+reg
            float* __restrict__ op = out + (size_t)bc * HH * WW;
#pragma unroll
            for (int tt = 0; tt < 8; ++tt) {
#pragma unroll
                for (int r = 0; r < 4; ++r) {
                    const int y = ty0 + 16 * wv + qd * 4 + r;
                    const int xcol = tx0 + 16 * tt + mrow;
                    op[(size_t)y * WW + xcol] = acc[tt][r];
                }
            }
        }
        __syncthreads();   // buf[(i+1)&1] staged AND buf[i&1] fully consumed
    }
}

extern "C" void kernel_launch(void* const* d_in, const int* in_sizes, int n_in,
                              void* d_out, int out_size, void* d_ws, size_t ws_size,
                              hipStream_t stream) {
    const float* x   = (const float*)d_in[0];
    const float* ker = (const float*)d_in[1];
    float* out = (float*)d_out;
    unsigned short* wsB = (unsigned short*)d_ws;   // 32*16896*2 = 1,081,344 B

    build_B<<<BB, 256, 0, stream>>>(ker, wsB);

    dwconv_mfma<<<NBLK, NTHREADS, 0, stream>>>(x, wsB, out);
}

// Round 5
// 218.394 us; speedup vs baseline: 1.3907x; 1.3907x over previous
//
#include <hip/hip_runtime.h>

#define KK 21
#define HH 512
#define WW 512
#define CC 3
#define BB 32
#define TILE_Y 64
#define TILE_X 128
#define SROWS 85        // 2-kh packing reads rows up to 16*3+15+1+2*10 = 84
#define SSTRIDE 168     // ushort elems/row; 336 B = odd multiple of 16B -> conflict-free reads
#define NKHP 11         // ceil(21/2) kh-pairs; kh=21 is a zero row in B
#define NB_PER_B (NKHP * 3 * 512)   // 16896 bf16 elems per batch
#define NCHUNK 20       // 8-ushort (16B) staging chunks per row: lc in [0,160)
#define NBLK (BB * CC * 32)         // 3072 blocks = 8 XCDs * 384

typedef __attribute__((ext_vector_type(8))) short short8;
typedef __attribute__((ext_vector_type(4))) float floatx4;

__device__ __forceinline__ unsigned short f2bf(float f) {
    union { float f; unsigned u; } v; v.f = f;
    unsigned r = v.u + 0x7FFF + ((v.u >> 16) & 1);   // RNE
    return (unsigned short)(r >> 16);
}

// ---- kernel 1: build banded-Toeplitz B fragments (2 kernel rows packed per K=32) ----
// el = khp*1536 + half*512 + (q*16 + n)*8 + j   (bf16)
// k = q*8+j; h = k>>4 (selects kernel row 2*khp+h); c = k&15
// tap d = c - n - 2 + 16*half  (staged origin gx = tx0 - 12 + lc)
__global__ __launch_bounds__(256) void build_B(
    const float* __restrict__ ker, unsigned short* __restrict__ wsB)
{
    const int b = blockIdx.x;
    const float* __restrict__ kp = ker + b * KK * KK;
    unsigned short* __restrict__ wb = wsB + (size_t)b * NB_PER_B;
    for (int e = threadIdx.x; e < NB_PER_B; e += 256) {
        const int j    = e & 7;
        const int n    = (e >> 3) & 15;
        const int q    = (e >> 7) & 3;
        const int f    = e >> 9;           // khp*3 + half
        const int khp  = f / 3;
        const int half = f - khp * 3;
        const int k    = q * 8 + j;
        const int h    = k >> 4;
        const int c    = k & 15;
        const int kh   = 2 * khp + h;
        const int d    = c - n - 2 + 16 * half;
        float v = 0.0f;
        if (kh < KK && d >= 0 && d < KK) v = kp[kh * KK + d];
        wb[e] = f2bf(v);
    }
}

// ---- kernel 2: main MFMA conv, 2 kernel rows per MFMA (K = 2 x 16 cols) ----
// Round-1 structure (stage -> sync -> compute), occupancy-maximized:
// 28560 B LDS -> 5 blocks/CU; __launch_bounds__(256,5) raises the cap to 20 waves/CU.
__global__ __launch_bounds__(256, 5) void dwconv_mfma(
    const float* __restrict__ x,
    const unsigned short* __restrict__ wsB,
    float* __restrict__ out)
{
    __shared__ __align__(16) unsigned short s_in[SROWS * SSTRIDE];  // 28560 B

    // bijective XCD-aware remap: 3072 = 8 XCDs * 384; XCD x gets rbid [384x, 384x+384)
    const int rbid = (blockIdx.x & 7) * (NBLK / 8) + (blockIdx.x >> 3);
    const int tiles = (HH / TILE_Y) * (WW / TILE_X);   // 32
    const int bc = rbid / tiles;                        // 0..95 (image*channel)
    const int t  = rbid % tiles;
    const int ty0 = (t / (WW / TILE_X)) * TILE_Y;
    const int tx0 = (t % (WW / TILE_X)) * TILE_X;
    const int b = bc / CC;

    const float* __restrict__ xp = x + (size_t)bc * HH * WW;
    const unsigned short* __restrict__ wsb = wsB + (size_t)b * NB_PER_B;
    const int tid = threadIdx.x;

    // ---- stage 85-row window as bf16: 2x float4 global load -> 1x b128 LDS write ----
    // staged col lc <-> gx = tx0 - 12 + lc; writes at 16B-unit 21*ly + k: conflict-free
    for (int i = tid; i < SROWS * NCHUNK; i += 256) {
        const int ly  = i / NCHUNK;
        const int k   = i - ly * NCHUNK;
        const int gy  = ty0 - 10 + ly;
        const int gx0 = tx0 - 12 + 8 * k;              // multiple of 4 -> float4 aligned
        float4 v0 = make_float4(0.f, 0.f, 0.f, 0.f);
        float4 v1 = make_float4(0.f, 0.f, 0.f, 0.f);
        if (gy >= 0 && gy < HH) {
            const float* __restrict__ rp = xp + (size_t)gy * WW;
            if (gx0 >= 0 && gx0 + 7 < WW) {
                v0 = *(const float4*)(rp + gx0);
                v1 = *(const float4*)(rp + gx0 + 4);
            } else {
                if (gx0 + 0 >= 0 && gx0 + 0 < WW) v0.x = rp[gx0 + 0];
                if (gx0 + 1 >= 0 && gx0 + 1 < WW) v0.y = rp[gx0 + 1];
                if (gx0 + 2 >= 0 && gx0 + 2 < WW) v0.z = rp[gx0 + 2];
                if (gx0 + 3 >= 0 && gx0 + 3 < WW) v0.w = rp[gx0 + 3];
                if (gx0 + 4 >= 0 && gx0 + 4 < WW) v1.x = rp[gx0 + 4];
                if (gx0 + 5 >= 0 && gx0 + 5 < WW) v1.y = rp[gx0 + 5];
                if (gx0 + 6 >= 0 && gx0 + 6 < WW) v1.z = rp[gx0 + 6];
                if (gx0 + 7 >= 0 && gx0 + 7 < WW) v1.w = rp[gx0 + 7];
            }
        }
        const int p0 = (int)((unsigned)f2bf(v0.x) | ((unsigned)f2bf(v0.y) << 16));
        const int p1 = (int)((unsigned)f2bf(v0.z) | ((unsigned)f2bf(v0.w) << 16));
        const int p2 = (int)((unsigned)f2bf(v1.x) | ((unsigned)f2bf(v1.y) << 16));
        const int p3 = (int)((unsigned)f2bf(v1.z) | ((unsigned)f2bf(v1.w) << 16));
        *(int4*)&s_in[ly * SSTRIDE + 8 * k] = make_int4(p0, p1, p2, p3);  // 16B aligned
    }
    __syncthreads();

    const int lane = tid & 63;
    const int wv   = tid >> 6;       // wave 0..3 -> output rows 16*wv..+15
    const int mrow = lane & 15;      // A's m / B's n / D's col
    const int qd   = lane >> 4;      // k-chunk: h = qd>>1 (kernel row), col half = qd&1

    floatx4 acc[8];
#pragma unroll
    for (int tt = 0; tt < 8; ++tt) acc[tt] = (floatx4){0.f, 0.f, 0.f, 0.f};

    const unsigned short* bbase = wsb + lane * 8;     // (q*16+n)*8+j with q=qd, n=mrow
    const unsigned short* abase = s_in + ((16 * wv + mrow + (qd >> 1)) * SSTRIDE) + 8 * (qd & 1);

    short8 nb1 = *(const short8*)(bbase);
    short8 nb2 = *(const short8*)(bbase + 512);
    short8 nb3 = *(const short8*)(bbase + 1024);

#pragma unroll 1
    for (int khp = 0; khp < NKHP; ++khp) {
        const short8 b1 = nb1;
        const short8 b2 = nb2;
        const short8 b3 = nb3;
        const int khn = (khp < NKHP - 1) ? (khp + 1) : khp;   // clamped prefetch
        nb1 = *(const short8*)(bbase + khn * 1536);
        nb2 = *(const short8*)(bbase + khn * 1536 + 512);
        nb3 = *(const short8*)(bbase + khn * 1536 + 1024);

        const unsigned short* arow = abase + 2 * khp * SSTRIDE;
        short8 a[10];
#pragma unroll
        for (int s = 0; s < 10; ++s) a[s] = *(const short8*)(arow + 16 * s);

#pragma unroll
        for (int tt = 0; tt < 8; ++tt) {
            acc[tt] = __builtin_amdgcn_mfma_f32_16x16x32_bf16(a[tt],     b1, acc[tt], 0, 0, 0);
            acc[tt] = __builtin_amdgcn_mfma_f32_16x16x32_bf16(a[tt + 1], b2, acc[tt], 0, 0, 0);
            acc[tt] = __builtin_amdgcn_mfma_f32_16x16x32_bf16(a[tt + 2], b3, acc[tt], 0, 0, 0);
        }
    }

    // ---- epilogue: D layout col=lane&15, row=(lane>>4)*4+reg ----
    float* __restrict__ op = out + (size_t)bc * HH * WW;
#pragma unroll
    for (int tt = 0; tt < 8; ++tt) {
#pragma unroll
        for (int r = 0; r < 4; ++r) {
            const int y = ty0 + 16 * wv + qd * 4 + r;
            const int xcol = tx0 + 16 * tt + mrow;
            op[(size_t)y * WW + xcol] = acc[tt][r];
        }
    }
}

extern "C" void kernel_launch(void* const* d_in, const int* in_sizes, int n_in,
                              void* d_out, int out_size, void* d_ws, size_t ws_size,
                              hipStream_t stream) {
    const float* x   = (const float*)d_in[0];
    const float* ker = (const float*)d_in[1];
    float* out = (float*)d_out;
    unsigned short* wsB = (unsigned short*)d_ws;   // 32*16896*2 = 1,081,344 B

    build_B<<<BB, 256, 0, stream>>>(ker, wsB);

    dwconv_mfma<<<NBLK, 256, 0, stream>>>(x, wsB, out);
}